// Round 1
// baseline (579.454 us; speedup 1.0000x reference)
//
#include <hip/hip_runtime.h>
#include <hip/hip_bf16.h>
#include <math.h>

typedef __attribute__((ext_vector_type(8))) short bf16x8;
typedef __attribute__((ext_vector_type(4))) float f32x4;

__device__ __forceinline__ f32x4 mfma16(bf16x8 a, bf16x8 b, f32x4 c) {
  return __builtin_amdgcn_mfma_f32_16x16x32_bf16(a, b, c, 0, 0, 0);
}

// ------------------------------------------------------------------
// Kernel 1: global mean / std (ddof=1) of sgap and pcount (norm01 stats)
// ------------------------------------------------------------------
__global__ void stats_kernel(const int* __restrict__ sgap,
                             const int* __restrict__ pcount,
                             float* __restrict__ stats) {
  const int N = 16 * 512;
  long long s0 = 0, q0 = 0, s1 = 0, q1 = 0;
  for (int i = threadIdx.x; i < N; i += 256) {
    long long a = sgap[i];
    long long b = pcount[i];
    s0 += a; q0 += a * a;
    s1 += b; q1 += b * b;
  }
#pragma unroll
  for (int m = 32; m >= 1; m >>= 1) {
    s0 += __shfl_xor(s0, m, 64); q0 += __shfl_xor(q0, m, 64);
    s1 += __shfl_xor(s1, m, 64); q1 += __shfl_xor(q1, m, 64);
  }
  __shared__ long long red[4][4];
  const int w = threadIdx.x >> 6;
  if ((threadIdx.x & 63) == 0) {
    red[w][0] = s0; red[w][1] = q0; red[w][2] = s1; red[w][3] = q1;
  }
  __syncthreads();
  if (threadIdx.x == 0) {
    long long S0 = 0, Q0 = 0, S1 = 0, Q1 = 0;
    for (int i = 0; i < 4; ++i) {
      S0 += red[i][0]; Q0 += red[i][1]; S1 += red[i][2]; Q1 += red[i][3];
    }
    const double n = (double)N;
    const double mean0 = S0 / n, mean1 = S1 / n;
    const double var0 = ((double)Q0 - (double)S0 * (double)S0 / n) / (n - 1.0);
    const double var1 = ((double)Q1 - (double)S1 * (double)S1 / n) / (n - 1.0);
    const float std0 = (float)sqrt(var0) + 1e-6f;
    const float std1 = (float)sqrt(var1) + 1e-6f;
    stats[0] = (float)mean0; stats[1] = 1.0f / std0;
    stats[2] = (float)mean1; stats[3] = 1.0f / std1;
  }
}

// ------------------------------------------------------------------
// Kernel 2: GEMM  out[r,c] = sum_k A[r,k] * W[c,k] + bias[c]
// M = 8192 rows, N = 512 cols, K = 512. 128x128 tile, BK=32, 4 waves.
// AMODE: 0 = A is float, 1 = A is bf16.
// OMODE: 0 = scatter bf16 to [b,h,S,64] (Q/K heads)
//        1 = scatter bf16 to [b,h,64,S] (V transposed)
//        2 = plain f32 [r,c]
// ------------------------------------------------------------------
template <int AMODE, int OMODE>
__global__ __launch_bounds__(256) void gemm512(const void* __restrict__ Ain,
                                               const float* __restrict__ W,
                                               const float* __restrict__ bias,
                                               void* __restrict__ Out) {
  constexpr int LDK = 40;  // padded bf16 stride (80 B): conflict-friendly, 16B-aligned
  __shared__ __hip_bfloat16 As[128 * LDK];
  __shared__ __hip_bfloat16 Bs[128 * LDK];
  const int tid = threadIdx.x;
  const int tm = blockIdx.x * 128;
  const int tn = blockIdx.y * 128;
  const int lane = tid & 63;
  const int wid = tid >> 6;
  const int wm = (wid >> 1) * 64;
  const int wn = (wid & 1) * 64;
  const int g = lane >> 4, l15 = lane & 15;

  const f32x4 Z = {0.f, 0.f, 0.f, 0.f};
  f32x4 acc[4][4];
#pragma unroll
  for (int m = 0; m < 4; ++m)
#pragma unroll
    for (int n = 0; n < 4; ++n) acc[m][n] = Z;

  for (int k0 = 0; k0 < 512; k0 += 32) {
#pragma unroll
    for (int p = 0; p < 4; ++p) {
      const int c = p * 256 + tid;
      const int row = c >> 3;        // 8 4-elem chunks per 32-wide row
      const int kc = (c & 7) * 4;
      union { __hip_bfloat16 h[4]; uint2 u; } ua, ub;
      if (AMODE == 0) {
        const float4 x = *(const float4*)((const float*)Ain + (size_t)(tm + row) * 512 + k0 + kc);
        ua.h[0] = __float2bfloat16(x.x); ua.h[1] = __float2bfloat16(x.y);
        ua.h[2] = __float2bfloat16(x.z); ua.h[3] = __float2bfloat16(x.w);
      } else {
        ua.u = *(const uint2*)((const __hip_bfloat16*)Ain + (size_t)(tm + row) * 512 + k0 + kc);
      }
      const float4 wv = *(const float4*)(W + (size_t)(tn + row) * 512 + k0 + kc);
      ub.h[0] = __float2bfloat16(wv.x); ub.h[1] = __float2bfloat16(wv.y);
      ub.h[2] = __float2bfloat16(wv.z); ub.h[3] = __float2bfloat16(wv.w);
      *(uint2*)&As[row * LDK + kc] = ua.u;
      *(uint2*)&Bs[row * LDK + kc] = ub.u;
    }
    __syncthreads();
    bf16x8 af[4], bfv[4];
#pragma unroll
    for (int m = 0; m < 4; ++m)
      af[m] = *(const bf16x8*)&As[(wm + m * 16 + l15) * LDK + g * 8];
#pragma unroll
    for (int n = 0; n < 4; ++n)
      bfv[n] = *(const bf16x8*)&Bs[(wn + n * 16 + l15) * LDK + g * 8];
#pragma unroll
    for (int m = 0; m < 4; ++m)
#pragma unroll
      for (int n = 0; n < 4; ++n)
        acc[m][n] = mfma16(af[m], bfv[n], acc[m][n]);
    __syncthreads();
  }

#pragma unroll
  for (int n = 0; n < 4; ++n) {
    const int cc = tn + wn + n * 16 + l15;
    const float bv = bias[cc];
#pragma unroll
    for (int m = 0; m < 4; ++m) {
#pragma unroll
      for (int jj = 0; jj < 4; ++jj) {
        const int r = tm + wm + m * 16 + g * 4 + jj;  // D row = (lane>>4)*4 + reg
        const float v = acc[m][n][jj] + bv;
        if (OMODE == 2) {
          ((float*)Out)[(size_t)r * 512 + cc] = v;
        } else {
          const int bb = r >> 9, srow = r & 511, hh = cc >> 6, dd = cc & 63;
          if (OMODE == 0)
            ((__hip_bfloat16*)Out)[(((size_t)(bb * 8 + hh)) * 512 + srow) * 64 + dd] =
                __float2bfloat16(v);
          else
            ((__hip_bfloat16*)Out)[(((size_t)(bb * 8 + hh)) * 64 + dd) * 512 + srow] =
                __float2bfloat16(v);
        }
      }
    }
  }
}

// ------------------------------------------------------------------
// Kernel 3: attention with temporal-distance reweighting.
// 1 wave = 16 query rows of one (b,h). Block = 4 waves = 64 rows.
// Whole score row (512) kept in registers (32 x f32x4).
// ------------------------------------------------------------------
__global__ __launch_bounds__(256, 2) void attn_kernel(
    const __hip_bfloat16* __restrict__ qh, const __hip_bfloat16* __restrict__ kh,
    const __hip_bfloat16* __restrict__ vhT, const float* __restrict__ gammas,
    __hip_bfloat16* __restrict__ Xb) {
  constexpr int PLD = 40;  // bf16 row stride of P tile (80 B)
  __shared__ __hip_bfloat16 Psh[4][2][16 * PLD];
  const int tid = threadIdx.x;
  const int lane = tid & 63;
  const int w = tid >> 6;
  const int bh = blockIdx.x >> 3;
  const int i0 = (blockIdx.x & 7) * 64 + w * 16;
  const int h = bh & 7, b = bh >> 3;
  const int g = lane >> 4, l15 = lane & 15;

  const __hip_bfloat16* Q = qh + (size_t)bh * (512 * 64);
  const __hip_bfloat16* K = kh + (size_t)bh * (512 * 64);
  const __hip_bfloat16* V = vhT + (size_t)bh * (64 * 512);

  const float gam = -log1pf(expf(gammas[h]));  // -softplus(gamma)
  const float scale = 0.125f;                  // 1/sqrt(64)

  const bf16x8 qf0 = *(const bf16x8*)&Q[(i0 + l15) * 64 + g * 8];
  const bf16x8 qf1 = *(const bf16x8*)&Q[(i0 + l15) * 64 + 32 + g * 8];

  const int ntile = i0 / 16 + 1;  // j-tiles with any valid (j < i) entries
  const f32x4 Z = {0.f, 0.f, 0.f, 0.f};

  // ---- pass 1: scores into registers; softmax denominator (no offset:
  // scores are O(+-8), exp fp32-safe; shift-invariance keeps it exact) ----
  f32x4 sreg[32];
  float d1p[4] = {0.f, 0.f, 0.f, 0.f};
#pragma unroll
  for (int t = 0; t < 32; ++t) {
    if (t < ntile) {
      const bf16x8 kf0 = *(const bf16x8*)&K[(t * 16 + l15) * 64 + g * 8];
      const bf16x8 kf1 = *(const bf16x8*)&K[(t * 16 + l15) * 64 + 32 + g * 8];
      f32x4 s = mfma16(qf0, kf0, Z);
      s = mfma16(qf1, kf1, s);
      sreg[t] = s;
      const int j = t * 16 + l15;
#pragma unroll
      for (int jj = 0; jj < 4; ++jj) {
        const int i = i0 + g * 4 + jj;  // D row = (lane>>4)*4 + reg
        d1p[jj] += (j < i) ? expf(s[jj] * scale) : 0.f;
      }
    }
  }
  float invd1[4];
#pragma unroll
  for (int jj = 0; jj < 4; ++jj) {
    float dd = d1p[jj];
#pragma unroll
    for (int m = 8; m >= 1; m >>= 1) dd += __shfl_xor(dd, m, 16);
    invd1[jj] = dd > 0.f ? 1.f / dd : 0.f;  // row 0 has no valid j -> 0
  }

  // ---- pass 2: p, suffix-cumsum, temporal, second softmax, PV ----
  f32x4 accx[4];
#pragma unroll
  for (int n = 0; n < 4; ++n) accx[n] = Z;
  float carry[4] = {0.f, 0.f, 0.f, 0.f};
  float d2p[4] = {0.f, 0.f, 0.f, 0.f};

#pragma unroll
  for (int tp = 0; tp < 16; ++tp) {
    if (tp * 2 < ntile) {
      __hip_bfloat16* Pw = &Psh[w][tp & 1][0];
#pragma unroll
      for (int half = 0; half < 2; ++half) {
        const int t = tp * 2 + half;
        float e2v[4] = {0.f, 0.f, 0.f, 0.f};
        if (t < ntile) {
          const f32x4 s = sreg[t];
          const int j = t * 16 + l15;
#pragma unroll
          for (int jj = 0; jj < 4; ++jj) {
            const int i = i0 + g * 4 + jj;
            const bool valid = j < i;
            const float sv = s[jj] * scale;
            const float p = valid ? expf(sv) * invd1[jj] : 0.f;
            // inclusive scan over the 16 lanes (ascending j)
            float cs = p;
#pragma unroll
            for (int dlt = 1; dlt < 16; dlt <<= 1) {
              const float o = __shfl_up(cs, dlt, 16);
              if (l15 >= dlt) cs += o;
            }
            const float suffix = 1.f - (carry[jj] + cs);  // disttotal - distcum
            carry[jj] += __shfl(cs, 15, 16);
            const float dist = sqrtf(fmaxf(suffix * (float)(i - j), 0.f));
            const float tempo = fmaxf(expf(gam * dist), 1e-5f);  // clip lower; exp<=1 so no upper clip
            const float e2 = valid ? expf(sv * tempo) : 0.f;
            d2p[jj] += e2;
            e2v[jj] = e2;
          }
        }
#pragma unroll
        for (int jj = 0; jj < 4; ++jj)
          Pw[(g * 4 + jj) * PLD + half * 16 + l15] = __float2bfloat16(e2v[jj]);
      }
      // same-wave LDS visibility (DS ops complete in order after lgkmcnt(0))
      asm volatile("s_waitcnt lgkmcnt(0)" ::: "memory");
      const bf16x8 pf = *(const bf16x8*)&Pw[l15 * PLD + g * 8];
#pragma unroll
      for (int n = 0; n < 4; ++n) {
        const bf16x8 vf =
            *(const bf16x8*)&V[(size_t)(n * 16 + l15) * 512 + tp * 32 + g * 8];
        accx[n] = mfma16(pf, vf, accx[n]);
      }
    }
  }

#pragma unroll
  for (int jj = 0; jj < 4; ++jj) {
    float dd = d2p[jj];
#pragma unroll
    for (int m = 8; m >= 1; m >>= 1) dd += __shfl_xor(dd, m, 16);
    d2p[jj] = dd;
  }
#pragma unroll
  for (int n = 0; n < 4; ++n) {
#pragma unroll
    for (int jj = 0; jj < 4; ++jj) {
      const int i = i0 + g * 4 + jj;
      const float val = (i > 0) ? accx[n][jj] / d2p[jj] : 0.f;  // zero_pad row 0
      Xb[((size_t)(b * 512 + i)) * 512 + h * 64 + n * 16 + l15] = __float2bfloat16(val);
    }
  }
}

// ------------------------------------------------------------------
// Kernel 4: interference MLP + residual add + LayerNorm -> bf16 Yn.
// Block = 16 tokens x 16 threads.
// ------------------------------------------------------------------
__global__ __launch_bounds__(256) void addnorm_kernel(
    const __hip_bfloat16* __restrict__ Xb, const int* __restrict__ sgap,
    const int* __restrict__ pcount, const float* __restrict__ stats,
    const float* __restrict__ Wi1, const float* __restrict__ bi1,
    const float* __restrict__ Wi2, const float* __restrict__ bi2,
    const float* __restrict__ iscale, const float* __restrict__ ln_g,
    const float* __restrict__ ln_b, __hip_bfloat16* __restrict__ Yn) {
  __shared__ float hid[16][128];
  __shared__ float iis[16][2];
  const int tid = threadIdx.x;
  const int tg = tid >> 4, l16 = tid & 15;
  const int t0 = blockIdx.x * 16;

  if (tid < 32) {
    const int tt = tid >> 1, c = tid & 1;
    const int raw = (c == 0) ? sgap[t0 + tt] : pcount[t0 + tt];
    const float mu = stats[c * 2], rs = stats[c * 2 + 1];
    iis[tt][c] = (tanhf(((float)raw - mu) * rs) + 1.f) * 0.5f;
  }
  __syncthreads();
  const float a = iis[tg][0], bb = iis[tg][1];
#pragma unroll
  for (int kk = 0; kk < 8; ++kk) {
    const int j = l16 + 16 * kk;
    hid[tg][j] = fmaxf(Wi1[j * 2] * a + Wi1[j * 2 + 1] * bb + bi1[j], 0.f);
  }
  __syncthreads();

  const float sc = iscale[0];
  float Yv[32];
  float sum = 0.f, sumsq = 0.f;
#pragma unroll
  for (int kk = 0; kk < 32; ++kk) {
    const int d = l16 + 16 * kk;
    const float4* wrow = (const float4*)&Wi2[(size_t)d * 128];
    float acc = bi2[d];
#pragma unroll 8
    for (int j4 = 0; j4 < 32; ++j4) {
      const float4 wv = wrow[j4];
      const float4 hv = *(const float4*)&hid[tg][j4 * 4];
      acc += wv.x * hv.x + wv.y * hv.y + wv.z * hv.z + wv.w * hv.w;
    }
    const float y = __bfloat162float(Xb[(size_t)(t0 + tg) * 512 + d]) + sc * acc;
    Yv[kk] = y;
    sum += y;
    sumsq += y * y;
  }
#pragma unroll
  for (int m = 8; m >= 1; m >>= 1) {
    sum += __shfl_xor(sum, m, 16);
    sumsq += __shfl_xor(sumsq, m, 16);
  }
  const float mu = sum * (1.f / 512.f);
  const float var = sumsq * (1.f / 512.f) - mu * mu;  // ddof=0
  const float rstd = rsqrtf(var + 1e-5f);
#pragma unroll
  for (int kk = 0; kk < 32; ++kk) {
    const int d = l16 + 16 * kk;
    Yn[(size_t)(t0 + tg) * 512 + d] =
        __float2bfloat16((Yv[kk] - mu) * rstd * ln_g[d] + ln_b[d]);
  }
}

// ------------------------------------------------------------------
extern "C" void kernel_launch(void* const* d_in, const int* in_sizes, int n_in,
                              void* d_out, int out_size, void* d_ws, size_t ws_size,
                              hipStream_t stream) {
  const float* q = (const float*)d_in[0];
  const float* k = (const float*)d_in[1];
  const float* v = (const float*)d_in[2];
  const int* sgap = (const int*)d_in[3];
  const int* pcount = (const int*)d_in[4];
  const float* Wq = (const float*)d_in[5];
  const float* bq = (const float*)d_in[6];
  const float* Wk = (const float*)d_in[7];
  const float* bk = (const float*)d_in[8];
  const float* Wv = (const float*)d_in[9];
  const float* bv = (const float*)d_in[10];
  const float* Wo = (const float*)d_in[11];
  const float* bo = (const float*)d_in[12];
  const float* gammas = (const float*)d_in[13];
  const float* ln_g = (const float*)d_in[14];
  const float* ln_b = (const float*)d_in[15];
  const float* Wi1 = (const float*)d_in[16];
  const float* bi1 = (const float*)d_in[17];
  const float* Wi2 = (const float*)d_in[18];
  const float* bi2 = (const float*)d_in[19];
  const float* iscale = (const float*)d_in[20];

  char* ws = (char*)d_ws;
  __hip_bfloat16* qh = (__hip_bfloat16*)(ws);
  __hip_bfloat16* kh = (__hip_bfloat16*)(ws + ((size_t)8 << 20));
  __hip_bfloat16* vhT = (__hip_bfloat16*)(ws + ((size_t)16 << 20));
  __hip_bfloat16* Xb = (__hip_bfloat16*)(ws + ((size_t)24 << 20));
  __hip_bfloat16* Yn = (__hip_bfloat16*)(ws + ((size_t)32 << 20));
  float* stats = (float*)(ws + ((size_t)40 << 20));

  stats_kernel<<<1, 256, 0, stream>>>(sgap, pcount, stats);
  gemm512<0, 0><<<dim3(64, 4), 256, 0, stream>>>(q, Wq, bq, qh);
  gemm512<0, 0><<<dim3(64, 4), 256, 0, stream>>>(k, Wk, bk, kh);
  gemm512<0, 1><<<dim3(64, 4), 256, 0, stream>>>(v, Wv, bv, vhT);
  attn_kernel<<<1024, 256, 0, stream>>>(qh, kh, vhT, gammas, Xb);
  addnorm_kernel<<<512, 256, 0, stream>>>(Xb, sgap, pcount, stats, Wi1, bi1, Wi2,
                                          bi2, iscale, ln_g, ln_b, Yn);
  gemm512<1, 2><<<dim3(64, 4), 256, 0, stream>>>(Yn, Wo, bo, d_out);
}

// Round 2
// 369.851 us; speedup vs baseline: 1.5667x; 1.5667x over previous
//
#include <hip/hip_runtime.h>
#include <hip/hip_bf16.h>
#include <math.h>

typedef __attribute__((ext_vector_type(8))) short bf16x8;
typedef __attribute__((ext_vector_type(4))) float f32x4;

__device__ __forceinline__ f32x4 mfma16(bf16x8 a, bf16x8 b, f32x4 c) {
  return __builtin_amdgcn_mfma_f32_16x16x32_bf16(a, b, c, 0, 0, 0);
}

// ------------------------------------------------------------------
// Kernel 1: global mean / std (ddof=1) of sgap and pcount (norm01 stats)
// ------------------------------------------------------------------
__global__ void stats_kernel(const int* __restrict__ sgap,
                             const int* __restrict__ pcount,
                             float* __restrict__ stats) {
  const int N = 16 * 512;
  long long s0 = 0, q0 = 0, s1 = 0, q1 = 0;
  for (int i = threadIdx.x; i < N; i += 256) {
    long long a = sgap[i];
    long long b = pcount[i];
    s0 += a; q0 += a * a;
    s1 += b; q1 += b * b;
  }
#pragma unroll
  for (int m = 32; m >= 1; m >>= 1) {
    s0 += __shfl_xor(s0, m, 64); q0 += __shfl_xor(q0, m, 64);
    s1 += __shfl_xor(s1, m, 64); q1 += __shfl_xor(q1, m, 64);
  }
  __shared__ long long red[4][4];
  const int w = threadIdx.x >> 6;
  if ((threadIdx.x & 63) == 0) {
    red[w][0] = s0; red[w][1] = q0; red[w][2] = s1; red[w][3] = q1;
  }
  __syncthreads();
  if (threadIdx.x == 0) {
    long long S0 = 0, Q0 = 0, S1 = 0, Q1 = 0;
    for (int i = 0; i < 4; ++i) {
      S0 += red[i][0]; Q0 += red[i][1]; S1 += red[i][2]; Q1 += red[i][3];
    }
    const double n = (double)N;
    const double mean0 = S0 / n, mean1 = S1 / n;
    const double var0 = ((double)Q0 - (double)S0 * (double)S0 / n) / (n - 1.0);
    const double var1 = ((double)Q1 - (double)S1 * (double)S1 / n) / (n - 1.0);
    const float std0 = (float)sqrt(var0) + 1e-6f;
    const float std1 = (float)sqrt(var1) + 1e-6f;
    stats[0] = (float)mean0; stats[1] = 1.0f / std0;
    stats[2] = (float)mean1; stats[3] = 1.0f / std1;
  }
}

// ------------------------------------------------------------------
// Kernel 2: GEMM  out[r,c] = sum_k A[r,k] * W[c,k] + bias[c]
// M = 8192 rows, N = 512 cols, K = 512. 128x128 tile, BK=32, 4 waves.
// AMODE: 0 = A is float, 1 = A is bf16.
// OMODE: 0 = scatter bf16 to [b,h,S,64] (Q/K heads)
//        1 = scatter bf16 to [b,h,64,S] (V transposed)
//        2 = plain f32 [r,c]
// ------------------------------------------------------------------
template <int AMODE, int OMODE>
__global__ __launch_bounds__(256) void gemm512(const void* __restrict__ Ain,
                                               const float* __restrict__ W,
                                               const float* __restrict__ bias,
                                               void* __restrict__ Out) {
  constexpr int LDK = 40;  // padded bf16 stride (80 B): conflict-friendly, 16B-aligned
  __shared__ __hip_bfloat16 As[128 * LDK];
  __shared__ __hip_bfloat16 Bs[128 * LDK];
  const int tid = threadIdx.x;
  const int tm = blockIdx.x * 128;
  const int tn = blockIdx.y * 128;
  const int lane = tid & 63;
  const int wid = tid >> 6;
  const int wm = (wid >> 1) * 64;
  const int wn = (wid & 1) * 64;
  const int g = lane >> 4, l15 = lane & 15;

  const f32x4 Z = {0.f, 0.f, 0.f, 0.f};
  f32x4 acc[4][4];
#pragma unroll
  for (int m = 0; m < 4; ++m)
#pragma unroll
    for (int n = 0; n < 4; ++n) acc[m][n] = Z;

  for (int k0 = 0; k0 < 512; k0 += 32) {
#pragma unroll
    for (int p = 0; p < 4; ++p) {
      const int c = p * 256 + tid;
      const int row = c >> 3;        // 8 4-elem chunks per 32-wide row
      const int kc = (c & 7) * 4;
      union { __hip_bfloat16 h[4]; uint2 u; } ua, ub;
      if (AMODE == 0) {
        const float4 x = *(const float4*)((const float*)Ain + (size_t)(tm + row) * 512 + k0 + kc);
        ua.h[0] = __float2bfloat16(x.x); ua.h[1] = __float2bfloat16(x.y);
        ua.h[2] = __float2bfloat16(x.z); ua.h[3] = __float2bfloat16(x.w);
      } else {
        ua.u = *(const uint2*)((const __hip_bfloat16*)Ain + (size_t)(tm + row) * 512 + k0 + kc);
      }
      const float4 wv = *(const float4*)(W + (size_t)(tn + row) * 512 + k0 + kc);
      ub.h[0] = __float2bfloat16(wv.x); ub.h[1] = __float2bfloat16(wv.y);
      ub.h[2] = __float2bfloat16(wv.z); ub.h[3] = __float2bfloat16(wv.w);
      *(uint2*)&As[row * LDK + kc] = ua.u;
      *(uint2*)&Bs[row * LDK + kc] = ub.u;
    }
    __syncthreads();
    bf16x8 af[4], bfv[4];
#pragma unroll
    for (int m = 0; m < 4; ++m)
      af[m] = *(const bf16x8*)&As[(wm + m * 16 + l15) * LDK + g * 8];
#pragma unroll
    for (int n = 0; n < 4; ++n)
      bfv[n] = *(const bf16x8*)&Bs[(wn + n * 16 + l15) * LDK + g * 8];
#pragma unroll
    for (int m = 0; m < 4; ++m)
#pragma unroll
      for (int n = 0; n < 4; ++n)
        acc[m][n] = mfma16(af[m], bfv[n], acc[m][n]);
    __syncthreads();
  }

#pragma unroll
  for (int n = 0; n < 4; ++n) {
    const int cc = tn + wn + n * 16 + l15;
    const float bv = bias[cc];
#pragma unroll
    for (int m = 0; m < 4; ++m) {
#pragma unroll
      for (int jj = 0; jj < 4; ++jj) {
        const int r = tm + wm + m * 16 + g * 4 + jj;  // D row = (lane>>4)*4 + reg
        const float v = acc[m][n][jj] + bv;
        if (OMODE == 2) {
          ((float*)Out)[(size_t)r * 512 + cc] = v;
        } else {
          const int bb = r >> 9, srow = r & 511, hh = cc >> 6, dd = cc & 63;
          if (OMODE == 0)
            ((__hip_bfloat16*)Out)[(((size_t)(bb * 8 + hh)) * 512 + srow) * 64 + dd] =
                __float2bfloat16(v);
          else
            ((__hip_bfloat16*)Out)[(((size_t)(bb * 8 + hh)) * 64 + dd) * 512 + srow] =
                __float2bfloat16(v);
        }
      }
    }
  }
}

// ------------------------------------------------------------------
// Kernel 3: attention with temporal-distance reweighting.
// 1 wave = 16 query rows of one (b,h). Block = 4 waves = 64 rows.
// Whole score row (512) kept in registers (32 x f32x4).
// ------------------------------------------------------------------
__global__ __launch_bounds__(256, 2) void attn_kernel(
    const __hip_bfloat16* __restrict__ qh, const __hip_bfloat16* __restrict__ kh,
    const __hip_bfloat16* __restrict__ vhT, const float* __restrict__ gammas,
    __hip_bfloat16* __restrict__ Xb) {
  constexpr int PLD = 40;  // bf16 row stride of P tile (80 B)
  __shared__ __hip_bfloat16 Psh[4][2][16 * PLD];
  const int tid = threadIdx.x;
  const int lane = tid & 63;
  const int w = tid >> 6;
  const int bh = blockIdx.x >> 3;
  const int i0 = (blockIdx.x & 7) * 64 + w * 16;
  const int h = bh & 7, b = bh >> 3;
  const int g = lane >> 4, l15 = lane & 15;

  const __hip_bfloat16* Q = qh + (size_t)bh * (512 * 64);
  const __hip_bfloat16* K = kh + (size_t)bh * (512 * 64);
  const __hip_bfloat16* V = vhT + (size_t)bh * (64 * 512);

  const float gam = -log1pf(expf(gammas[h]));  // -softplus(gamma)
  const float scale = 0.125f;                  // 1/sqrt(64)

  const bf16x8 qf0 = *(const bf16x8*)&Q[(i0 + l15) * 64 + g * 8];
  const bf16x8 qf1 = *(const bf16x8*)&Q[(i0 + l15) * 64 + 32 + g * 8];

  const int ntile = i0 / 16 + 1;  // j-tiles with any valid (j < i) entries
  const f32x4 Z = {0.f, 0.f, 0.f, 0.f};

  // ---- pass 1: scores into registers; softmax denominator (no offset:
  // scores are O(+-8), exp fp32-safe; shift-invariance keeps it exact) ----
  f32x4 sreg[32];
  float d1p[4] = {0.f, 0.f, 0.f, 0.f};
#pragma unroll
  for (int t = 0; t < 32; ++t) {
    if (t < ntile) {
      const bf16x8 kf0 = *(const bf16x8*)&K[(t * 16 + l15) * 64 + g * 8];
      const bf16x8 kf1 = *(const bf16x8*)&K[(t * 16 + l15) * 64 + 32 + g * 8];
      f32x4 s = mfma16(qf0, kf0, Z);
      s = mfma16(qf1, kf1, s);
      sreg[t] = s;
      const int j = t * 16 + l15;
#pragma unroll
      for (int jj = 0; jj < 4; ++jj) {
        const int i = i0 + g * 4 + jj;  // D row = (lane>>4)*4 + reg
        d1p[jj] += (j < i) ? expf(s[jj] * scale) : 0.f;
      }
    }
  }
  float invd1[4];
#pragma unroll
  for (int jj = 0; jj < 4; ++jj) {
    float dd = d1p[jj];
#pragma unroll
    for (int m = 8; m >= 1; m >>= 1) dd += __shfl_xor(dd, m, 16);
    invd1[jj] = dd > 0.f ? 1.f / dd : 0.f;  // row 0 has no valid j -> 0
  }

  // ---- pass 2: p, suffix-cumsum, temporal, second softmax, PV ----
  f32x4 accx[4];
#pragma unroll
  for (int n = 0; n < 4; ++n) accx[n] = Z;
  float carry[4] = {0.f, 0.f, 0.f, 0.f};
  float d2p[4] = {0.f, 0.f, 0.f, 0.f};

#pragma unroll
  for (int tp = 0; tp < 16; ++tp) {
    if (tp * 2 < ntile) {
      __hip_bfloat16* Pw = &Psh[w][tp & 1][0];
#pragma unroll
      for (int half = 0; half < 2; ++half) {
        const int t = tp * 2 + half;
        float e2v[4] = {0.f, 0.f, 0.f, 0.f};
        if (t < ntile) {
          const f32x4 s = sreg[t];
          const int j = t * 16 + l15;
#pragma unroll
          for (int jj = 0; jj < 4; ++jj) {
            const int i = i0 + g * 4 + jj;
            const bool valid = j < i;
            const float sv = s[jj] * scale;
            const float p = valid ? expf(sv) * invd1[jj] : 0.f;
            // inclusive scan over the 16 lanes (ascending j)
            float cs = p;
#pragma unroll
            for (int dlt = 1; dlt < 16; dlt <<= 1) {
              const float o = __shfl_up(cs, dlt, 16);
              if (l15 >= dlt) cs += o;
            }
            const float suffix = 1.f - (carry[jj] + cs);  // disttotal - distcum
            carry[jj] += __shfl(cs, 15, 16);
            const float dist = sqrtf(fmaxf(suffix * (float)(i - j), 0.f));
            const float tempo = fmaxf(expf(gam * dist), 1e-5f);  // clip lower; exp<=1 so no upper clip
            const float e2 = valid ? expf(sv * tempo) : 0.f;
            d2p[jj] += e2;
            e2v[jj] = e2;
          }
        }
#pragma unroll
        for (int jj = 0; jj < 4; ++jj)
          Pw[(g * 4 + jj) * PLD + half * 16 + l15] = __float2bfloat16(e2v[jj]);
      }
      // same-wave LDS visibility (DS ops complete in order after lgkmcnt(0))
      asm volatile("s_waitcnt lgkmcnt(0)" ::: "memory");
      const bf16x8 pf = *(const bf16x8*)&Pw[l15 * PLD + g * 8];
#pragma unroll
      for (int n = 0; n < 4; ++n) {
        const bf16x8 vf =
            *(const bf16x8*)&V[(size_t)(n * 16 + l15) * 512 + tp * 32 + g * 8];
        accx[n] = mfma16(pf, vf, accx[n]);
      }
    }
  }

#pragma unroll
  for (int jj = 0; jj < 4; ++jj) {
    float dd = d2p[jj];
#pragma unroll
    for (int m = 8; m >= 1; m >>= 1) dd += __shfl_xor(dd, m, 16);
    d2p[jj] = dd;
  }
#pragma unroll
  for (int n = 0; n < 4; ++n) {
#pragma unroll
    for (int jj = 0; jj < 4; ++jj) {
      const int i = i0 + g * 4 + jj;
      const float val = (i > 0) ? accx[n][jj] / d2p[jj] : 0.f;  // zero_pad row 0
      Xb[((size_t)(b * 512 + i)) * 512 + h * 64 + n * 16 + l15] = __float2bfloat16(val);
    }
  }
}

// ------------------------------------------------------------------
// Kernel 4 (v2): interference MLP + residual + LayerNorm via MFMA.
// Block = 256 thr (4 waves) handles 64 tokens; grid = 128.
// feat[64 x 512] = H[64 x 128] @ Wi2^T, Wi2 staged to LDS bf16 in
// two 256-col halves (87 KB LDS total). LN fused with shuffle+LDS reduce.
// ------------------------------------------------------------------
__global__ __launch_bounds__(256) void addnorm_kernel(
    const __hip_bfloat16* __restrict__ Xb, const int* __restrict__ sgap,
    const int* __restrict__ pcount, const float* __restrict__ stats,
    const float* __restrict__ Wi1, const float* __restrict__ bi1,
    const float* __restrict__ Wi2, const float* __restrict__ bi2,
    const float* __restrict__ iscale, const float* __restrict__ ln_g,
    const float* __restrict__ ln_b, __hip_bfloat16* __restrict__ Yn) {
  constexpr int WLD = 132;  // bf16 stride 264 B -> +2 banks/row, 16 lanes conflict-free
  __shared__ __hip_bfloat16 Wt[256 * WLD];  // one 256-col half of Wi2 (bf16)
  __shared__ __hip_bfloat16 Hs[64 * WLD];   // hidden (bf16)
  __shared__ float iis[64][2];
  __shared__ float red[4][64][2];
  const int tid = threadIdx.x;
  const int lane = tid & 63;
  const int w = tid >> 6;
  const int g = lane >> 4, l15 = lane & 15;
  const int t0 = blockIdx.x * 64;

  // interference inputs (2 per token)
  if (tid < 64) {
    const float a0 = ((float)sgap[t0 + tid] - stats[0]) * stats[1];
    const float a1 = ((float)pcount[t0 + tid] - stats[2]) * stats[3];
    iis[tid][0] = (tanhf(a0) + 1.f) * 0.5f;
    iis[tid][1] = (tanhf(a1) + 1.f) * 0.5f;
  }
  __syncthreads();

  // hidden H[64][128]: thread -> token tid&63, j-range w*32..+32
  {
    const int tt = tid & 63;
    const int jb = w * 32;  // wave-uniform -> Wi1/bi1 loads are broadcast
    const float a = iis[tt][0], b = iis[tt][1];
#pragma unroll
    for (int jj = 0; jj < 32; ++jj) {
      const int j = jb + jj;
      const float hv = fmaxf(Wi1[j * 2] * a + Wi1[j * 2 + 1] * b + bi1[j], 0.f);
      Hs[tt * WLD + j] = __float2bfloat16(hv);
    }
  }

  const f32x4 Z = {0.f, 0.f, 0.f, 0.f};
  f32x4 acc[4][8];
#pragma unroll
  for (int m = 0; m < 4; ++m)
#pragma unroll
    for (int n = 0; n < 8; ++n) acc[m][n] = Z;

  for (int half = 0; half < 2; ++half) {
    if (half) __syncthreads();  // drain previous half's reads before overwrite
    // stage Wi2 rows [half*256, half*256+256) -> Wt (f32 -> bf16), coalesced
#pragma unroll
    for (int p = 0; p < 32; ++p) {
      const int idx = p * 256 + tid;   // float4 index; 32 per row
      const int r = idx >> 5;
      const int c4 = (idx & 31) * 4;
      const float4 x = *(const float4*)(Wi2 + ((size_t)(half * 256 + r)) * 128 + c4);
      union { __hip_bfloat16 h[4]; uint2 u; } ub;
      ub.h[0] = __float2bfloat16(x.x); ub.h[1] = __float2bfloat16(x.y);
      ub.h[2] = __float2bfloat16(x.z); ub.h[3] = __float2bfloat16(x.w);
      *(uint2*)&Wt[r * WLD + c4] = ub.u;
    }
    __syncthreads();  // Wt (and on half 0 also Hs) visible
#pragma unroll
    for (int k = 0; k < 4; ++k) {
      bf16x8 af[4];
#pragma unroll
      for (int m = 0; m < 4; ++m)
        af[m] = *(const bf16x8*)&Hs[(m * 16 + l15) * WLD + k * 32 + g * 8];
#pragma unroll
      for (int n = 0; n < 4; ++n) {
        const bf16x8 bf =
            *(const bf16x8*)&Wt[(w * 64 + n * 16 + l15) * WLD + k * 32 + g * 8];
#pragma unroll
        for (int m = 0; m < 4; ++m)
          acc[m][half * 4 + n] = mfma16(af[m], bf, acc[m][half * 4 + n]);
      }
    }
  }

  // per-column constants (col c = (nn>>2)*256 + w*64 + (nn&3)*16 + l15)
  const float sc = iscale[0];
  float bi[8], lg[8], lb[8];
#pragma unroll
  for (int nn = 0; nn < 8; ++nn) {
    const int c = (nn >> 2) * 256 + w * 64 + (nn & 3) * 16 + l15;
    bi[nn] = bi2[c]; lg[nn] = ln_g[c]; lb[nn] = ln_b[c];
  }

  // y = Xb + sc*(feat + bi2); accumulate row sums; acc overwritten with y
#pragma unroll
  for (int m = 0; m < 4; ++m) {
#pragma unroll
    for (int jj = 0; jj < 4; ++jj) {
      const int r = m * 16 + g * 4 + jj;  // local token row
      float s = 0.f, sq = 0.f;
#pragma unroll
      for (int nn = 0; nn < 8; ++nn) {
        const int c = (nn >> 2) * 256 + w * 64 + (nn & 3) * 16 + l15;
        const float fv = acc[m][nn][jj] + bi[nn];
        const float y =
            __bfloat162float(Xb[(size_t)(t0 + r) * 512 + c]) + sc * fv;
        acc[m][nn][jj] = y;
        s += y; sq += y * y;
      }
#pragma unroll
      for (int mk = 8; mk >= 1; mk >>= 1) {
        s += __shfl_xor(s, mk, 16);
        sq += __shfl_xor(sq, mk, 16);
      }
      if (l15 == 0) { red[w][r][0] = s; red[w][r][1] = sq; }
    }
  }
  __syncthreads();

#pragma unroll
  for (int m = 0; m < 4; ++m) {
#pragma unroll
    for (int jj = 0; jj < 4; ++jj) {
      const int r = m * 16 + g * 4 + jj;
      const float sum = red[0][r][0] + red[1][r][0] + red[2][r][0] + red[3][r][0];
      const float sqs = red[0][r][1] + red[1][r][1] + red[2][r][1] + red[3][r][1];
      const float mu = sum * (1.f / 512.f);
      const float var = sqs * (1.f / 512.f) - mu * mu;  // ddof=0
      const float rstd = rsqrtf(var + 1e-5f);
#pragma unroll
      for (int nn = 0; nn < 8; ++nn) {
        const int c = (nn >> 2) * 256 + w * 64 + (nn & 3) * 16 + l15;
        Yn[(size_t)(t0 + r) * 512 + c] =
            __float2bfloat16((acc[m][nn][jj] - mu) * rstd * lg[nn] + lb[nn]);
      }
    }
  }
}

// ------------------------------------------------------------------
extern "C" void kernel_launch(void* const* d_in, const int* in_sizes, int n_in,
                              void* d_out, int out_size, void* d_ws, size_t ws_size,
                              hipStream_t stream) {
  const float* q = (const float*)d_in[0];
  const float* k = (const float*)d_in[1];
  const float* v = (const float*)d_in[2];
  const int* sgap = (const int*)d_in[3];
  const int* pcount = (const int*)d_in[4];
  const float* Wq = (const float*)d_in[5];
  const float* bq = (const float*)d_in[6];
  const float* Wk = (const float*)d_in[7];
  const float* bk = (const float*)d_in[8];
  const float* Wv = (const float*)d_in[9];
  const float* bv = (const float*)d_in[10];
  const float* Wo = (const float*)d_in[11];
  const float* bo = (const float*)d_in[12];
  const float* gammas = (const float*)d_in[13];
  const float* ln_g = (const float*)d_in[14];
  const float* ln_b = (const float*)d_in[15];
  const float* Wi1 = (const float*)d_in[16];
  const float* bi1 = (const float*)d_in[17];
  const float* Wi2 = (const float*)d_in[18];
  const float* bi2 = (const float*)d_in[19];
  const float* iscale = (const float*)d_in[20];

  char* ws = (char*)d_ws;
  __hip_bfloat16* qh = (__hip_bfloat16*)(ws);
  __hip_bfloat16* kh = (__hip_bfloat16*)(ws + ((size_t)8 << 20));
  __hip_bfloat16* vhT = (__hip_bfloat16*)(ws + ((size_t)16 << 20));
  __hip_bfloat16* Xb = (__hip_bfloat16*)(ws + ((size_t)24 << 20));
  __hip_bfloat16* Yn = (__hip_bfloat16*)(ws + ((size_t)32 << 20));
  float* stats = (float*)(ws + ((size_t)40 << 20));

  stats_kernel<<<1, 256, 0, stream>>>(sgap, pcount, stats);
  gemm512<0, 0><<<dim3(64, 4), 256, 0, stream>>>(q, Wq, bq, qh);
  gemm512<0, 0><<<dim3(64, 4), 256, 0, stream>>>(k, Wk, bk, kh);
  gemm512<0, 1><<<dim3(64, 4), 256, 0, stream>>>(v, Wv, bv, vhT);
  attn_kernel<<<1024, 256, 0, stream>>>(qh, kh, vhT, gammas, Xb);
  addnorm_kernel<<<128, 256, 0, stream>>>(Xb, sgap, pcount, stats, Wi1, bi1, Wi2,
                                          bi2, iscale, ln_g, ln_b, Yn);
  gemm512<1, 2><<<dim3(64, 4), 256, 0, stream>>>(Yn, Wo, bo, d_out);
}

// Round 4
// 265.830 us; speedup vs baseline: 2.1798x; 1.3913x over previous
//
#include <hip/hip_runtime.h>
#include <hip/hip_bf16.h>
#include <math.h>

typedef __attribute__((ext_vector_type(8))) short bf16x8;
typedef __attribute__((ext_vector_type(4))) float f32x4;
typedef __fp16 __attribute__((ext_vector_type(2))) h16x2;

__device__ __forceinline__ f32x4 mfma16(bf16x8 a, bf16x8 b, f32x4 c) {
  return __builtin_amdgcn_mfma_f32_16x16x32_bf16(a, b, c, 0, 0, 0);
}

// inclusive scan across each 16-lane row (DPP row_shr, full VALU rate)
__device__ __forceinline__ float scan16(float x) {
  int v;
  v = __builtin_amdgcn_update_dpp(0, __float_as_int(x), 0x111, 0xf, 0xf, true);
  x += __int_as_float(v);
  v = __builtin_amdgcn_update_dpp(0, __float_as_int(x), 0x112, 0xf, 0xf, true);
  x += __int_as_float(v);
  v = __builtin_amdgcn_update_dpp(0, __float_as_int(x), 0x114, 0xf, 0xf, true);
  x += __int_as_float(v);
  v = __builtin_amdgcn_update_dpp(0, __float_as_int(x), 0x118, 0xf, 0xf, true);
  x += __int_as_float(v);
  return x;
}

// ------------------------------------------------------------------
// Kernel 1: global mean / std (ddof=1) of sgap and pcount (norm01 stats)
// ------------------------------------------------------------------
__global__ void stats_kernel(const int* __restrict__ sgap,
                             const int* __restrict__ pcount,
                             float* __restrict__ stats) {
  const int N = 16 * 512;
  long long s0 = 0, q0 = 0, s1 = 0, q1 = 0;
  for (int i = threadIdx.x; i < N; i += 256) {
    long long a = sgap[i];
    long long b = pcount[i];
    s0 += a; q0 += a * a;
    s1 += b; q1 += b * b;
  }
#pragma unroll
  for (int m = 32; m >= 1; m >>= 1) {
    s0 += __shfl_xor(s0, m, 64); q0 += __shfl_xor(q0, m, 64);
    s1 += __shfl_xor(s1, m, 64); q1 += __shfl_xor(q1, m, 64);
  }
  __shared__ long long red[4][4];
  const int w = threadIdx.x >> 6;
  if ((threadIdx.x & 63) == 0) {
    red[w][0] = s0; red[w][1] = q0; red[w][2] = s1; red[w][3] = q1;
  }
  __syncthreads();
  if (threadIdx.x == 0) {
    long long S0 = 0, Q0 = 0, S1 = 0, Q1 = 0;
    for (int i = 0; i < 4; ++i) {
      S0 += red[i][0]; Q0 += red[i][1]; S1 += red[i][2]; Q1 += red[i][3];
    }
    const double n = (double)N;
    const double mean0 = S0 / n, mean1 = S1 / n;
    const double var0 = ((double)Q0 - (double)S0 * (double)S0 / n) / (n - 1.0);
    const double var1 = ((double)Q1 - (double)S1 * (double)S1 / n) / (n - 1.0);
    const float std0 = (float)sqrt(var0) + 1e-6f;
    const float std1 = (float)sqrt(var1) + 1e-6f;
    stats[0] = (float)mean0; stats[1] = 1.0f / std0;
    stats[2] = (float)mean1; stats[3] = 1.0f / std1;
  }
}

// ------------------------------------------------------------------
// GEMM body  out[r,c] = sum_k A[r,k] * W[c,k] + bias[c]
// M = 8192, N = 512, K = 512. 128x128 tile, BK=32, 4 waves.
// AMODE: 0 = A float, 1 = A bf16.
// omode: 0 -> bf16 [b,h,S,64]; 1 -> bf16 [b,h,64,S] (V^T); 2 -> f32 [r,c]
// ------------------------------------------------------------------
template <int AMODE>
__device__ __forceinline__ void gemm_body(const void* __restrict__ Ain,
                                          const float* __restrict__ W,
                                          const float* __restrict__ bias,
                                          void* __restrict__ Out, const int omode) {
  constexpr int LDK = 40;
  __shared__ __hip_bfloat16 As[128 * LDK];
  __shared__ __hip_bfloat16 Bs[128 * LDK];
  const int tid = threadIdx.x;
  const int tm = blockIdx.x * 128;
  const int tn = blockIdx.y * 128;
  const int lane = tid & 63;
  const int wid = tid >> 6;
  const int wm = (wid >> 1) * 64;
  const int wn = (wid & 1) * 64;
  const int g = lane >> 4, l15 = lane & 15;

  const f32x4 Z = {0.f, 0.f, 0.f, 0.f};
  f32x4 acc[4][4];
#pragma unroll
  for (int m = 0; m < 4; ++m)
#pragma unroll
    for (int n = 0; n < 4; ++n) acc[m][n] = Z;

  for (int k0 = 0; k0 < 512; k0 += 32) {
#pragma unroll
    for (int p = 0; p < 4; ++p) {
      const int c = p * 256 + tid;
      const int row = c >> 3;
      const int kc = (c & 7) * 4;
      union { __hip_bfloat16 h[4]; uint2 u; } ua, ub;
      if (AMODE == 0) {
        const float4 x = *(const float4*)((const float*)Ain + (size_t)(tm + row) * 512 + k0 + kc);
        ua.h[0] = __float2bfloat16(x.x); ua.h[1] = __float2bfloat16(x.y);
        ua.h[2] = __float2bfloat16(x.z); ua.h[3] = __float2bfloat16(x.w);
      } else {
        ua.u = *(const uint2*)((const __hip_bfloat16*)Ain + (size_t)(tm + row) * 512 + k0 + kc);
      }
      const float4 wv = *(const float4*)(W + (size_t)(tn + row) * 512 + k0 + kc);
      ub.h[0] = __float2bfloat16(wv.x); ub.h[1] = __float2bfloat16(wv.y);
      ub.h[2] = __float2bfloat16(wv.z); ub.h[3] = __float2bfloat16(wv.w);
      *(uint2*)&As[row * LDK + kc] = ua.u;
      *(uint2*)&Bs[row * LDK + kc] = ub.u;
    }
    __syncthreads();
    bf16x8 af[4], bfv[4];
#pragma unroll
    for (int m = 0; m < 4; ++m)
      af[m] = *(const bf16x8*)&As[(wm + m * 16 + l15) * LDK + g * 8];
#pragma unroll
    for (int n = 0; n < 4; ++n)
      bfv[n] = *(const bf16x8*)&Bs[(wn + n * 16 + l15) * LDK + g * 8];
#pragma unroll
    for (int m = 0; m < 4; ++m)
#pragma unroll
      for (int n = 0; n < 4; ++n)
        acc[m][n] = mfma16(af[m], bfv[n], acc[m][n]);
    __syncthreads();
  }

#pragma unroll
  for (int n = 0; n < 4; ++n) {
    const int cc = tn + wn + n * 16 + l15;
    const float bv = bias[cc];
#pragma unroll
    for (int m = 0; m < 4; ++m) {
#pragma unroll
      for (int jj = 0; jj < 4; ++jj) {
        const int r = tm + wm + m * 16 + g * 4 + jj;
        const float v = acc[m][n][jj] + bv;
        if (omode == 2) {
          ((float*)Out)[(size_t)r * 512 + cc] = v;
        } else {
          const int bb = r >> 9, srow = r & 511, hh = cc >> 6, dd = cc & 63;
          if (omode == 0)
            ((__hip_bfloat16*)Out)[(((size_t)(bb * 8 + hh)) * 512 + srow) * 64 + dd] =
                __float2bfloat16(v);
          else
            ((__hip_bfloat16*)Out)[(((size_t)(bb * 8 + hh)) * 64 + dd) * 512 + srow] =
                __float2bfloat16(v);
        }
      }
    }
  }
}

// fused Q/K/V projection: blockIdx.z selects which of the three
__global__ __launch_bounds__(256) void gemm_qkv(
    const float* __restrict__ q, const float* __restrict__ k,
    const float* __restrict__ v, const float* __restrict__ Wq,
    const float* __restrict__ bq, const float* __restrict__ Wk,
    const float* __restrict__ bk, const float* __restrict__ Wv,
    const float* __restrict__ bv, __hip_bfloat16* __restrict__ qh,
    __hip_bfloat16* __restrict__ kh, __hip_bfloat16* __restrict__ vhT) {
  const int z = blockIdx.z;
  const float* A = (z == 0) ? q : (z == 1) ? k : v;
  const float* W = (z == 0) ? Wq : (z == 1) ? Wk : Wv;
  const float* bias = (z == 0) ? bq : (z == 1) ? bk : bv;
  void* Out = (z == 0) ? (void*)qh : (z == 1) ? (void*)kh : (void*)vhT;
  gemm_body<0>(A, W, bias, Out, (z == 2) ? 1 : 0);
}

__global__ __launch_bounds__(256) void gemm_wo(const __hip_bfloat16* __restrict__ Yn,
                                               const float* __restrict__ Wo,
                                               const float* __restrict__ bo,
                                               float* __restrict__ Out) {
  gemm_body<1>(Yn, Wo, bo, Out, 2);
}

// ------------------------------------------------------------------
// Attention unit: 1 wave computes 16 query rows (i0..i0+15) of one (b,h).
// ntile = i0/16 + 1 j-tiles. Scores packed f16 in registers.
// ------------------------------------------------------------------
#define PLD 40

__device__ __forceinline__ void attn_unit(
    const __hip_bfloat16* __restrict__ Q, const __hip_bfloat16* __restrict__ K,
    const __hip_bfloat16* __restrict__ V, __hip_bfloat16* __restrict__ Xb,
    __hip_bfloat16* Pw, const int i0, const int ntile, const float gam,
    const int b, const int h, const int lane) {
  const int g = lane >> 4, l15 = lane & 15;
  const float scale = 0.125f;  // 1/sqrt(64)
  const f32x4 Z = {0.f, 0.f, 0.f, 0.f};

  const bf16x8 qf0 = *(const bf16x8*)&Q[(i0 + l15) * 64 + g * 8];
  const bf16x8 qf1 = *(const bf16x8*)&Q[(i0 + l15) * 64 + 32 + g * 8];

  // ---- pass 1: scores -> packed f16 regs; softmax-1 denominator ----
  h16x2 sp[64];
  float d1p[4] = {0.f, 0.f, 0.f, 0.f};
#pragma unroll
  for (int t = 0; t < 32; ++t) {
    if (t < ntile) {
      const bf16x8 kf0 = *(const bf16x8*)&K[(t * 16 + l15) * 64 + g * 8];
      const bf16x8 kf1 = *(const bf16x8*)&K[(t * 16 + l15) * 64 + 32 + g * 8];
      f32x4 s = mfma16(qf0, kf0, Z);
      s = mfma16(qf1, kf1, s);
      sp[2 * t] = __builtin_amdgcn_cvt_pkrtz(s[0] * scale, s[1] * scale);
      sp[2 * t + 1] = __builtin_amdgcn_cvt_pkrtz(s[2] * scale, s[3] * scale);
      const int j = t * 16 + l15;
#pragma unroll
      for (int jj = 0; jj < 4; ++jj) {
        const float sv = (float)((jj < 2) ? sp[2 * t][jj] : sp[2 * t + 1][jj - 2]);
        const int i = i0 + g * 4 + jj;
        d1p[jj] += (j < i) ? __expf(sv) : 0.f;
      }
    }
  }
  float invd1[4];
#pragma unroll
  for (int jj = 0; jj < 4; ++jj) {
    float dd = d1p[jj];
#pragma unroll
    for (int m = 8; m >= 1; m >>= 1) dd += __shfl_xor(dd, m, 16);
    invd1[jj] = dd > 0.f ? 1.f / dd : 0.f;  // row 0: no valid j
  }

  // ---- pass 2: p, DPP suffix-cumsum, temporal, softmax-2, PV ----
  f32x4 accx[4] = {Z, Z, Z, Z};
  float carry[4] = {0.f, 0.f, 0.f, 0.f};
  float d2p[4] = {0.f, 0.f, 0.f, 0.f};

#pragma unroll
  for (int tp = 0; tp < 16; ++tp) {
    if (tp * 2 < ntile) {
      __hip_bfloat16* Pb = Pw + (tp & 1) * (16 * PLD);
#pragma unroll
      for (int half = 0; half < 2; ++half) {
        const int t = tp * 2 + half;
        float e2v[4] = {0.f, 0.f, 0.f, 0.f};
        if (t < ntile) {
          const int j = t * 16 + l15;
#pragma unroll
          for (int jj = 0; jj < 4; ++jj) {
            const float sv = (float)((jj < 2) ? sp[2 * t][jj] : sp[2 * t + 1][jj - 2]);
            const int i = i0 + g * 4 + jj;
            const bool valid = j < i;
            const float p = valid ? __expf(sv) * invd1[jj] : 0.f;
            const float cs = scan16(p) + carry[jj];     // inclusive cum (j asc)
            const float suffix = 1.f - cs;              // disttotal - distcum
            carry[jj] = __shfl(cs, 15, 16);             // 1 LDS op per row-half
            const float dist = sqrtf(fmaxf(suffix * (float)(i - j), 0.f));
            const float tempo = fmaxf(__expf(gam * dist), 1e-5f);
            const float e2 = valid ? __expf(sv * tempo) : 0.f;
            d2p[jj] += e2;
            e2v[jj] = e2;
          }
        }
#pragma unroll
        for (int jj = 0; jj < 4; ++jj)
          Pb[(g * 4 + jj) * PLD + half * 16 + l15] = __float2bfloat16(e2v[jj]);
      }
      // same-wave LDS visibility; "memory" clobber orders the ds ops
      asm volatile("s_waitcnt lgkmcnt(0)" ::: "memory");
      const bf16x8 pf = *(const bf16x8*)&Pb[l15 * PLD + g * 8];
#pragma unroll
      for (int n = 0; n < 4; ++n) {
        const bf16x8 vf =
            *(const bf16x8*)&V[(size_t)(n * 16 + l15) * 512 + tp * 32 + g * 8];
        accx[n] = mfma16(pf, vf, accx[n]);
      }
    }
  }

#pragma unroll
  for (int jj = 0; jj < 4; ++jj) {
    float dd = d2p[jj];
#pragma unroll
    for (int m = 8; m >= 1; m >>= 1) dd += __shfl_xor(dd, m, 16);
    d2p[jj] = dd > 0.f ? 1.f / dd : 0.f;
  }
#pragma unroll
  for (int n = 0; n < 4; ++n) {
#pragma unroll
    for (int jj = 0; jj < 4; ++jj) {
      const int i = i0 + g * 4 + jj;
      const float val = (i > 0) ? accx[n][jj] * d2p[jj] : 0.f;  // zero_pad row 0
      Xb[((size_t)(b * 512 + i)) * 512 + h * 64 + n * 16 + l15] = __float2bfloat16(val);
    }
  }
}

// 1-wave blocks; pair row-group p with 31-p -> uniform 33 tiles/wave.
// XCD swizzle keeps each bh's K/V in one L2.
__global__ __launch_bounds__(64) void attn_kernel(
    const __hip_bfloat16* __restrict__ qh, const __hip_bfloat16* __restrict__ kh,
    const __hip_bfloat16* __restrict__ vhT, const float* __restrict__ gammas,
    __hip_bfloat16* __restrict__ Xb) {
  __shared__ __hip_bfloat16 Psh[2 * 16 * PLD];
  const int lane = threadIdx.x;
  const int work = (blockIdx.x & 7) * 256 + (blockIdx.x >> 3);  // 2048 % 8 == 0
  const int bh = work >> 4;
  const int pr = work & 15;
  const int b = bh >> 3, h = bh & 7;

  const __hip_bfloat16* Q = qh + (size_t)bh * (512 * 64);
  const __hip_bfloat16* K = kh + (size_t)bh * (512 * 64);
  const __hip_bfloat16* V = vhT + (size_t)bh * (64 * 512);
  const float gam = -log1pf(expf(gammas[h]));  // -softplus

  attn_unit(Q, K, V, Xb, Psh, pr * 16, pr + 1, gam, b, h, lane);
  attn_unit(Q, K, V, Xb, Psh, (31 - pr) * 16, 32 - pr, gam, b, h, lane);
}

// ------------------------------------------------------------------
// Interference MLP + residual + LayerNorm via MFMA (unchanged from R2)
// ------------------------------------------------------------------
__global__ __launch_bounds__(256) void addnorm_kernel(
    const __hip_bfloat16* __restrict__ Xb, const int* __restrict__ sgap,
    const int* __restrict__ pcount, const float* __restrict__ stats,
    const float* __restrict__ Wi1, const float* __restrict__ bi1,
    const float* __restrict__ Wi2, const float* __restrict__ bi2,
    const float* __restrict__ iscale, const float* __restrict__ ln_g,
    const float* __restrict__ ln_b, __hip_bfloat16* __restrict__ Yn) {
  constexpr int WLD = 132;
  __shared__ __hip_bfloat16 Wt[256 * WLD];
  __shared__ __hip_bfloat16 Hs[64 * WLD];
  __shared__ float iis[64][2];
  __shared__ float red[4][64][2];
  const int tid = threadIdx.x;
  const int lane = tid & 63;
  const int w = tid >> 6;
  const int g = lane >> 4, l15 = lane & 15;
  const int t0 = blockIdx.x * 64;

  if (tid < 64) {
    const float a0 = ((float)sgap[t0 + tid] - stats[0]) * stats[1];
    const float a1 = ((float)pcount[t0 + tid] - stats[2]) * stats[3];
    iis[tid][0] = (tanhf(a0) + 1.f) * 0.5f;
    iis[tid][1] = (tanhf(a1) + 1.f) * 0.5f;
  }
  __syncthreads();

  {
    const int tt = tid & 63;
    const int jb = w * 32;
    const float a = iis[tt][0], b = iis[tt][1];
#pragma unroll
    for (int jj = 0; jj < 32; ++jj) {
      const int j = jb + jj;
      const float hv = fmaxf(Wi1[j * 2] * a + Wi1[j * 2 + 1] * b + bi1[j], 0.f);
      Hs[tt * WLD + j] = __float2bfloat16(hv);
    }
  }

  const f32x4 Z = {0.f, 0.f, 0.f, 0.f};
  f32x4 acc[4][8];
#pragma unroll
  for (int m = 0; m < 4; ++m)
#pragma unroll
    for (int n = 0; n < 8; ++n) acc[m][n] = Z;

  for (int half = 0; half < 2; ++half) {
    if (half) __syncthreads();
#pragma unroll
    for (int p = 0; p < 32; ++p) {
      const int idx = p * 256 + tid;
      const int r = idx >> 5;
      const int c4 = (idx & 31) * 4;
      const float4 x = *(const float4*)(Wi2 + ((size_t)(half * 256 + r)) * 128 + c4);
      union { __hip_bfloat16 h[4]; uint2 u; } ub;
      ub.h[0] = __float2bfloat16(x.x); ub.h[1] = __float2bfloat16(x.y);
      ub.h[2] = __float2bfloat16(x.z); ub.h[3] = __float2bfloat16(x.w);
      *(uint2*)&Wt[r * WLD + c4] = ub.u;
    }
    __syncthreads();
#pragma unroll
    for (int k = 0; k < 4; ++k) {
      bf16x8 af[4];
#pragma unroll
      for (int m = 0; m < 4; ++m)
        af[m] = *(const bf16x8*)&Hs[(m * 16 + l15) * WLD + k * 32 + g * 8];
#pragma unroll
      for (int n = 0; n < 4; ++n) {
        const bf16x8 bf =
            *(const bf16x8*)&Wt[(w * 64 + n * 16 + l15) * WLD + k * 32 + g * 8];
#pragma unroll
        for (int m = 0; m < 4; ++m)
          acc[m][half * 4 + n] = mfma16(af[m], bf, acc[m][half * 4 + n]);
      }
    }
  }

  const float sc = iscale[0];
  float bi[8], lg[8], lb[8];
#pragma unroll
  for (int nn = 0; nn < 8; ++nn) {
    const int c = (nn >> 2) * 256 + w * 64 + (nn & 3) * 16 + l15;
    bi[nn] = bi2[c]; lg[nn] = ln_g[c]; lb[nn] = ln_b[c];
  }

#pragma unroll
  for (int m = 0; m < 4; ++m) {
#pragma unroll
    for (int jj = 0; jj < 4; ++jj) {
      const int r = m * 16 + g * 4 + jj;
      float s = 0.f, sq = 0.f;
#pragma unroll
      for (int nn = 0; nn < 8; ++nn) {
        const int c = (nn >> 2) * 256 + w * 64 + (nn & 3) * 16 + l15;
        const float fv = acc[m][nn][jj] + bi[nn];
        const float y =
            __bfloat162float(Xb[(size_t)(t0 + r) * 512 + c]) + sc * fv;
        acc[m][nn][jj] = y;
        s += y; sq += y * y;
      }
#pragma unroll
      for (int mk = 8; mk >= 1; mk >>= 1) {
        s += __shfl_xor(s, mk, 16);
        sq += __shfl_xor(sq, mk, 16);
      }
      if (l15 == 0) { red[w][r][0] = s; red[w][r][1] = sq; }
    }
  }
  __syncthreads();

#pragma unroll
  for (int m = 0; m < 4; ++m) {
#pragma unroll
    for (int jj = 0; jj < 4; ++jj) {
      const int r = m * 16 + g * 4 + jj;
      const float sum = red[0][r][0] + red[1][r][0] + red[2][r][0] + red[3][r][0];
      const float sqs = red[0][r][1] + red[1][r][1] + red[2][r][1] + red[3][r][1];
      const float mu = sum * (1.f / 512.f);
      const float var = sqs * (1.f / 512.f) - mu * mu;
      const float rstd = rsqrtf(var + 1e-5f);
#pragma unroll
      for (int nn = 0; nn < 8; ++nn) {
        const int c = (nn >> 2) * 256 + w * 64 + (nn & 3) * 16 + l15;
        Yn[(size_t)(t0 + r) * 512 + c] =
            __float2bfloat16((acc[m][nn][jj] - mu) * rstd * lg[nn] + lb[nn]);
      }
    }
  }
}

// ------------------------------------------------------------------
extern "C" void kernel_launch(void* const* d_in, const int* in_sizes, int n_in,
                              void* d_out, int out_size, void* d_ws, size_t ws_size,
                              hipStream_t stream) {
  const float* q = (const float*)d_in[0];
  const float* k = (const float*)d_in[1];
  const float* v = (const float*)d_in[2];
  const int* sgap = (const int*)d_in[3];
  const int* pcount = (const int*)d_in[4];
  const float* Wq = (const float*)d_in[5];
  const float* bq = (const float*)d_in[6];
  const float* Wk = (const float*)d_in[7];
  const float* bk = (const float*)d_in[8];
  const float* Wv = (const float*)d_in[9];
  const float* bv = (const float*)d_in[10];
  const float* Wo = (const float*)d_in[11];
  const float* bo = (const float*)d_in[12];
  const float* gammas = (const float*)d_in[13];
  const float* ln_g = (const float*)d_in[14];
  const float* ln_b = (const float*)d_in[15];
  const float* Wi1 = (const float*)d_in[16];
  const float* bi1 = (const float*)d_in[17];
  const float* Wi2 = (const float*)d_in[18];
  const float* bi2 = (const float*)d_in[19];
  const float* iscale = (const float*)d_in[20];

  char* ws = (char*)d_ws;
  __hip_bfloat16* qh = (__hip_bfloat16*)(ws);
  __hip_bfloat16* kh = (__hip_bfloat16*)(ws + ((size_t)8 << 20));
  __hip_bfloat16* vhT = (__hip_bfloat16*)(ws + ((size_t)16 << 20));
  __hip_bfloat16* Xb = (__hip_bfloat16*)(ws + ((size_t)24 << 20));
  __hip_bfloat16* Yn = (__hip_bfloat16*)(ws + ((size_t)32 << 20));
  float* stats = (float*)(ws + ((size_t)40 << 20));

  stats_kernel<<<1, 256, 0, stream>>>(sgap, pcount, stats);
  gemm_qkv<<<dim3(64, 4, 3), 256, 0, stream>>>(q, k, v, Wq, bq, Wk, bk, Wv, bv,
                                               qh, kh, vhT);
  attn_kernel<<<2048, 64, 0, stream>>>(qh, kh, vhT, gammas, Xb);
  addnorm_kernel<<<128, 256, 0, stream>>>(Xb, sgap, pcount, stats, Wi1, bi1, Wi2,
                                          bi2, iscale, ln_g, ln_b, Yn);
  gemm_wo<<<dim3(64, 4), 256, 0, stream>>>(Yn, Wo, bo, (float*)d_out);
}